// Round 7
// baseline (30.358 us; speedup 1.0000x reference)
//
#include <hip/hip_runtime.h>
#include <math.h>

// Problem constants (fixed by the reference)
constexpr int D_MODEL = 1024;
constexpr int D_STATE = 64;
constexpr int SEQ_L   = 2048;
constexpr int BLOCK   = 256;
constexpr int DSPLIT  = 2;   // blocks per d-row: grid = D_MODEL*DSPLIT = 2048 -> 8 blocks/CU

typedef float f32x2 __attribute__((ext_vector_type(2)));
typedef float f32x4 __attribute__((ext_vector_type(4)));

// Forced VOP3P packed-fp32 (gfx950). Note: measured r5 vs r6 shows packed fp32
// is issue-rate-neutral on gfx950 (no 2x flop win); kept because it halves
// instruction COUNT per element vs scalar, which matters at the issue floor.
#define PK_MUL(d,a,b)    asm("v_pk_mul_f32 %0, %1, %2" : "=v"(d) : "v"(a), "v"(b))
#define PK_ADD(d,a,b)    asm("v_pk_add_f32 %0, %1, %2" : "=v"(d) : "v"(a), "v"(b))
#define PK_SUB(d,a,b)    asm("v_pk_add_f32 %0, %1, %2 neg_lo:[0,1] neg_hi:[0,1]" : "=v"(d) : "v"(a), "v"(b))
#define PK_FMA(d,a,b,c)  asm("v_pk_fma_f32 %0, %1, %2, %3" : "=v"(d) : "v"(a), "v"(b), "v"(c))
#define PK_FMA_ACC(acc,a,b) asm("v_pk_fma_f32 %0, %1, %2, %0" : "+v"(acc) : "v"(a), "v"(b))

// ---------------- fast path: real part only (harness keeps Re(H_z)) ----------
// Numerics: dr = 1 -/+ ur formed BEFORE squaring (the (1+|A|^2)-2u shortcut
// cancels catastrophically at resonance; round 3 failure).
// +/-z pairing: z(l+L/2) = -z(l) -> share u = A*z, ui^2.
// Batched rcp: 1/m1,1/m2 from rcp(m1*m2); m1*m2 can't underflow since
// dr1^2+dr2^2 = 2+2*ur^2 >= 2.
// Occupancy: 2048 blocks (8/CU), __launch_bounds__(256,8) caps VGPR at 64 so
// 8 waves/SIMD are resident to hide LDS latency + dep chains (r6 post-mortem:
// 4 waves/SIMD left ~50% stall).
__global__ __launch_bounds__(BLOCK, 8) void s4_cauchy_real_kernel(
    const float* __restrict__ log_dt,   // (D)
    const float* __restrict__ A_real,   // (D,N)
    const float* __restrict__ A_imag,   // (D,N)
    const float* __restrict__ C,        // (D,N,2)
    float* __restrict__ out)            // (D,L) float32 = Re(H_z)
{
    // {abr,abr,abi,abi} and {nr,nr,ni,ni}: one ds_read_b128 broadcast each
    __shared__ f32x4 s_c1[D_STATE];
    __shared__ f32x4 s_c2[D_STATE];

    const int d    = blockIdx.x >> 1;       // d-row
    const int half = blockIdx.x & 1;        // which half of the +z l-range
    const int tid  = threadIdx.x;

    if (tid < D_STATE) {
        const int n = tid;
        const float dt = __expf(log_dt[d]);
        const float ar = A_real[d * D_STATE + n];
        const float ai = A_imag[d * D_STATE + n];
        const float xr = 0.5f * dt * ar;          // x = dt*A/2
        const float xi = 0.5f * dt * ai;
        const float dr = 1.0f - xr;               // den = 1 - x
        const float di = -xi;
        const float inv = 1.0f / (dr * dr + di * di);
        const float pr = 1.0f + xr;               // A_bar = (1+x)/(1-x)
        const float pi = xi;
        const float abr = (pr * dr + pi * di) * inv;
        const float abi = (pi * dr - pr * di) * inv;
        const float bbr =  dt * dr * inv;         // B_bar = dt/(1-x)
        const float bbi = -dt * di * inv;
        const float cr = C[(d * D_STATE + n) * 2 + 0];
        const float ci = C[(d * D_STATE + n) * 2 + 1];
        const float nr = cr * bbr - ci * bbi;     // num = Cc * B_bar
        const float ni = cr * bbi + ci * bbr;
        s_c1[n] = (f32x4){abr, abr, abi, abi};
        s_c2[n] = (f32x4){nr, nr, ni, ni};
    }
    __syncthreads();

    // Thread owns 4 outputs: +z pair l_j = half*512 + tid + j*256 (j=0,1)
    // and -z mirrors l_j + 1024.
    const int lbase = half * (SEQ_L / 4) + tid;   // half*512 + tid
    f32x2 zr2, zi2, accP, accM;
#pragma unroll
    for (int j = 0; j < 2; ++j) {
        const int l = lbase + j * BLOCK;
        const float theta = (2.0f * 3.14159265358979323846f * (float)l) / (float)SEQ_L;
        float s, c;
        __sincosf(theta, &s, &c);
        zr2[j] = c;                                // z_inv = exp(-i*theta)
        zi2[j] = -s;
    }
    accP = (f32x2){0.0f, 0.0f};
    accM = (f32x2){0.0f, 0.0f};

    const f32x2 one = (f32x2){1.0f, 1.0f};

#pragma unroll 2
    for (int n = 0; n < D_STATE; ++n) {
        const f32x4 c1 = s_c1[n];                  // wave-uniform b128 broadcast
        const f32x4 c2 = s_c2[n];
        const f32x2 ab_r = __builtin_shufflevector(c1, c1, 0, 1);
        const f32x2 ab_i = __builtin_shufflevector(c1, c1, 2, 3);
        const f32x2 n_r  = __builtin_shufflevector(c2, c2, 0, 1);
        const f32x2 n_i  = __builtin_shufflevector(c2, c2, 2, 3);

        f32x2 t, ur, ui, uisq, dr1, dr2, mag1, mag2, w, num1, num2, mm, t1, t2;
        // u = A_bar * z_inv
        PK_MUL(t, ab_r, zr2);
        asm("v_pk_fma_f32 %0, %1, %2, %3 neg_lo:[1,0,0] neg_hi:[1,0,0]"
            : "=v"(ur) : "v"(ab_i), "v"(zi2), "v"(t));          // ur = -abi*zi + abr*zr
        PK_MUL(t, ab_r, zi2);
        PK_FMA(ui, ab_i, zr2, t);                               // ui = abi*zr + abr*zi
        PK_MUL(uisq, ui, ui);
        PK_SUB(dr1, one, ur);                                   // +z: dr1 = 1 - ur
        PK_ADD(dr2, one, ur);                                   // -z: dr2 = 1 + ur
        PK_FMA(mag1, dr1, dr1, uisq);
        PK_FMA(mag2, dr2, dr2, uisq);
        // w = nr*ur + ni*ui;  num1 = nr - w;  num2 = nr + w
        PK_MUL(w, n_r, ur);
        PK_FMA(w, n_i, ui, w);
        PK_SUB(num1, n_r, w);
        PK_ADD(num2, n_r, w);
        // batched reciprocal
        PK_MUL(mm, mag1, mag2);
        f32x2 r;
        r[0] = __builtin_amdgcn_rcpf(mm[0]);
        r[1] = __builtin_amdgcn_rcpf(mm[1]);
        PK_MUL(t1, num1, mag2);
        PK_MUL(t2, num2, mag1);
        PK_FMA_ACC(accP, t1, r);
        PK_FMA_ACC(accM, t2, r);
    }

#pragma unroll
    for (int j = 0; j < 2; ++j) {
        out[d * SEQ_L + lbase + j * BLOCK]                = accP[j];
        out[d * SEQ_L + lbase + j * BLOCK + SEQ_L / 2]    = accM[j];
    }
}

// ---------------- fallback: full complex output (if harness ever wants it) ---
__global__ __launch_bounds__(BLOCK) void s4_cauchy_complex_kernel(
    const float* __restrict__ log_dt, const float* __restrict__ A_real,
    const float* __restrict__ A_imag, const float* __restrict__ C,
    float* __restrict__ out)
{
    __shared__ float s_abr[D_STATE], s_abi[D_STATE], s_nr[D_STATE], s_ni[D_STATE];
    const int d    = blockIdx.x / (SEQ_L / BLOCK);
    const int lblk = blockIdx.x % (SEQ_L / BLOCK);
    const int tid  = threadIdx.x;
    if (tid < D_STATE) {
        const int n = tid;
        const float dt = __expf(log_dt[d]);
        const float ar = A_real[d * D_STATE + n], ai = A_imag[d * D_STATE + n];
        const float xr = 0.5f * dt * ar, xi = 0.5f * dt * ai;
        const float dr = 1.0f - xr, di = -xi;
        const float inv = 1.0f / (dr * dr + di * di);
        const float pr = 1.0f + xr, pi = xi;
        s_abr[n] = (pr * dr + pi * di) * inv;
        s_abi[n] = (pi * dr - pr * di) * inv;
        const float bbr = dt * dr * inv, bbi = -dt * di * inv;
        const float cr = C[(d * D_STATE + n) * 2 + 0], ci = C[(d * D_STATE + n) * 2 + 1];
        s_nr[n] = cr * bbr - ci * bbi;
        s_ni[n] = cr * bbi + ci * bbr;
    }
    __syncthreads();
    const int l = lblk * BLOCK + tid;
    const float theta = (2.0f * 3.14159265358979323846f * (float)l) / (float)SEQ_L;
    float s, c; __sincosf(theta, &s, &c);
    const float zr = c, zi = -s;
    float accr = 0.f, acci = 0.f;
#pragma unroll
    for (int n = 0; n < D_STATE; ++n) {
        const float abr = s_abr[n], abi = s_abi[n], nr = s_nr[n], ni = s_ni[n];
        const float dr = 1.0f - (abr * zr - abi * zi);
        const float di = -(abr * zi + abi * zr);
        const float inv = __builtin_amdgcn_rcpf(dr * dr + di * di);
        accr += (nr * dr + ni * di) * inv;
        acci += (ni * dr - nr * di) * inv;
    }
    float2* o = reinterpret_cast<float2*>(out);
    o[d * SEQ_L + l] = make_float2(accr, acci);
}

extern "C" void kernel_launch(void* const* d_in, const int* in_sizes, int n_in,
                              void* d_out, int out_size, void* d_ws, size_t ws_size,
                              hipStream_t stream) {
    const float* log_dt = (const float*)d_in[0];
    const float* A_real = (const float*)d_in[1];
    const float* A_imag = (const float*)d_in[2];
    const float* C      = (const float*)d_in[3];
    float* out = (float*)d_out;

    if (out_size >= 2 * D_MODEL * SEQ_L) {
        dim3 grid(D_MODEL * (SEQ_L / BLOCK));
        s4_cauchy_complex_kernel<<<grid, dim3(BLOCK), 0, stream>>>(log_dt, A_real, A_imag, C, out);
    } else {
        dim3 grid(D_MODEL * DSPLIT);  // 2048 blocks -> 8 blocks/CU
        s4_cauchy_real_kernel<<<grid, dim3(BLOCK), 0, stream>>>(log_dt, A_real, A_imag, C, out);
    }
}

// Round 8
// 27.440 us; speedup vs baseline: 1.1063x; 1.1063x over previous
//
#include <hip/hip_runtime.h>
#include <math.h>

// Problem constants (fixed by the reference)
constexpr int D_MODEL = 1024;
constexpr int D_STATE = 64;
constexpr int SEQ_L   = 2048;
constexpr int BLOCK   = 256;

typedef float f32x2 __attribute__((ext_vector_type(2)));
typedef float f32x4 __attribute__((ext_vector_type(4)));

// VOP3P packed-fp32. Measured (r5 vs r6): issue-rate-neutral vs scalar pairs
// (pk ~ 2 scalar slots), kept because instruction COUNT is the binding
// constraint (r5/r6/r7 evidence) and pk halves it.
#define PK_MUL(d,a,b)    asm("v_pk_mul_f32 %0, %1, %2" : "=v"(d) : "v"(a), "v"(b))
#define PK_ADD(d,a,b)    asm("v_pk_add_f32 %0, %1, %2" : "=v"(d) : "v"(a), "v"(b))
#define PK_SUB(d,a,b)    asm("v_pk_add_f32 %0, %1, %2 neg_lo:[0,1] neg_hi:[0,1]" : "=v"(d) : "v"(a), "v"(b))
#define PK_FMA(d,a,b,c)  asm("v_pk_fma_f32 %0, %1, %2, %3" : "=v"(d) : "v"(a), "v"(b), "v"(c))
#define PK_FMA_NEG0(d,a,b,c) asm("v_pk_fma_f32 %0, %1, %2, %3 neg_lo:[1,0,0] neg_hi:[1,0,0]" : "=v"(d) : "v"(a), "v"(b), "v"(c))
#define PK_FMA_ACC(acc,a,b) asm("v_pk_fma_f32 %0, %1, %2, %0" : "+v"(acc) : "v"(a), "v"(b))

// ---------------- fast path: real part only (harness keeps Re(H_z)) ----------
// Numerics: every denominator is (1 -/+ u_component)^2 + other^2, with the
// subtraction formed BEFORE squaring (the (1+|A|^2)-2u shortcut cancels
// catastrophically at resonance; round-3 failure).
// Quarter symmetry: z_inv(l + r*L/4) = (-i)^r z_inv(l), so one u = A*z_inv
// serves 4 rotations:  +z: mag=(1-ur)^2+ui^2, num=nr-w1
//                      -iz: mag=(1-ui)^2+ur^2, num=nr-w2
//                      -z: mag=(1+ur)^2+ui^2, num=nr+w1
//                      +iz: mag=(1+ui)^2+ur^2, num=nr+w2
// with w1 = nr*ur+ni*ui, w2 = nr*ui-ni*ur.
// Batched rcp pairs (P,M) and (J,K): magP*magM >= ~((1-|u|^2)^2 scale) can't
// have both factors tiny ((1-ur)^2+(1+ur)^2 >= 2); same for (J,K) in ui.
__global__ __launch_bounds__(BLOCK) void s4_cauchy_real_kernel(
    const float* __restrict__ log_dt,   // (D)
    const float* __restrict__ A_real,   // (D,N)
    const float* __restrict__ A_imag,   // (D,N)
    const float* __restrict__ C,        // (D,N,2)
    float* __restrict__ out)            // (D,L) float32 = Re(H_z)
{
    // {abr,abr,abi,abi} and {nr,nr,ni,ni}: one ds_read_b128 broadcast each
    __shared__ f32x4 s_c1[D_STATE];
    __shared__ f32x4 s_c2[D_STATE];

    const int d   = blockIdx.x;
    const int tid = threadIdx.x;

    if (tid < D_STATE) {
        const int n = tid;
        const float dt = __expf(log_dt[d]);
        const float ar = A_real[d * D_STATE + n];
        const float ai = A_imag[d * D_STATE + n];
        const float xr = 0.5f * dt * ar;          // x = dt*A/2
        const float xi = 0.5f * dt * ai;
        const float dr = 1.0f - xr;               // den = 1 - x
        const float di = -xi;
        const float inv = 1.0f / (dr * dr + di * di);
        const float pr = 1.0f + xr;               // A_bar = (1+x)/(1-x)
        const float pi = xi;
        const float abr = (pr * dr + pi * di) * inv;
        const float abi = (pi * dr - pr * di) * inv;
        const float bbr =  dt * dr * inv;         // B_bar = dt/(1-x)
        const float bbi = -dt * di * inv;
        const float cr = C[(d * D_STATE + n) * 2 + 0];
        const float ci = C[(d * D_STATE + n) * 2 + 1];
        const float nr = cr * bbr - ci * bbi;     // num = Cc * B_bar
        const float ni = cr * bbi + ci * bbr;
        s_c1[n] = (f32x4){abr, abr, abi, abi};
        s_c2[n] = (f32x4){nr, nr, ni, ni};
    }
    __syncthreads();

    // Thread owns 8 l's: l = tid + j*256 + r*512, j in {0,1} (packed lanes),
    // r in {0..3} (quarter rotations). All stores coalesced.
    f32x2 zr2, zi2;
#pragma unroll
    for (int j = 0; j < 2; ++j) {
        const int l = tid + j * BLOCK;
        const float theta = (2.0f * 3.14159265358979323846f * (float)l) / (float)SEQ_L;
        float s, c;
        __sincosf(theta, &s, &c);
        zr2[j] = c;                                // z_inv = exp(-i*theta)
        zi2[j] = -s;
    }
    f32x2 accP = (f32x2){0.0f, 0.0f};              // +z   -> l + 0
    f32x2 accJ = (f32x2){0.0f, 0.0f};              // -i z -> l + 512
    f32x2 accM = (f32x2){0.0f, 0.0f};              // -z   -> l + 1024
    f32x2 accK = (f32x2){0.0f, 0.0f};              // +i z -> l + 1536

    const f32x2 one = (f32x2){1.0f, 1.0f};

#pragma unroll 2
    for (int n = 0; n < D_STATE; ++n) {
        const f32x4 c1 = s_c1[n];                  // wave-uniform b128 broadcast
        const f32x4 c2 = s_c2[n];
        const f32x2 ab_r = __builtin_shufflevector(c1, c1, 0, 1);
        const f32x2 ab_i = __builtin_shufflevector(c1, c1, 2, 3);
        const f32x2 n_r  = __builtin_shufflevector(c2, c2, 0, 1);
        const f32x2 n_i  = __builtin_shufflevector(c2, c2, 2, 3);

        f32x2 t, t2, ur, ui, urq, uiq;
        // u = A_bar * z_inv
        PK_MUL(t, ab_r, zr2);
        PK_FMA_NEG0(ur, ab_i, zi2, t);             // ur = -abi*zi + abr*zr
        PK_MUL(t2, ab_r, zi2);
        PK_FMA(ui, ab_i, zr2, t2);                 // ui = abi*zr + abr*zi
        PK_MUL(urq, ur, ur);
        PK_MUL(uiq, ui, ui);
        // four rotation denominators (subtract-before-square)
        f32x2 drP, drM, drJ, drK, magP, magM, magJ, magK;
        PK_SUB(drP, one, ur);
        PK_ADD(drM, one, ur);
        PK_SUB(drJ, one, ui);
        PK_ADD(drK, one, ui);
        PK_FMA(magP, drP, drP, uiq);
        PK_FMA(magM, drM, drM, uiq);
        PK_FMA(magJ, drJ, drJ, urq);
        PK_FMA(magK, drK, drK, urq);
        // w1 = nr*ur + ni*ui ; w2 = nr*ui - ni*ur
        f32x2 w1, w2, numP, numM, numJ, numK;
        PK_MUL(t, n_r, ur);
        PK_FMA(w1, n_i, ui, t);
        PK_MUL(t2, n_r, ui);
        PK_FMA_NEG0(w2, n_i, ur, t2);
        PK_SUB(numP, n_r, w1);
        PK_ADD(numM, n_r, w1);
        PK_SUB(numJ, n_r, w2);
        PK_ADD(numK, n_r, w2);
        // batched reciprocals for the (P,M) and (J,K) pairs
        f32x2 mmA, mmB, rA, rB, tP, tM, tJ, tK;
        PK_MUL(mmA, magP, magM);
        PK_MUL(mmB, magJ, magK);
        rA[0] = __builtin_amdgcn_rcpf(mmA[0]);
        rA[1] = __builtin_amdgcn_rcpf(mmA[1]);
        rB[0] = __builtin_amdgcn_rcpf(mmB[0]);
        rB[1] = __builtin_amdgcn_rcpf(mmB[1]);
        PK_MUL(tP, numP, magM);
        PK_MUL(tM, numM, magP);
        PK_MUL(tJ, numJ, magK);
        PK_MUL(tK, numK, magJ);
        PK_FMA_ACC(accP, tP, rA);
        PK_FMA_ACC(accM, tM, rA);
        PK_FMA_ACC(accJ, tJ, rB);
        PK_FMA_ACC(accK, tK, rB);
    }

    float* o = out + d * SEQ_L + tid;
#pragma unroll
    for (int j = 0; j < 2; ++j) {
        o[j * BLOCK + 0 * (SEQ_L / 4)] = accP[j];
        o[j * BLOCK + 1 * (SEQ_L / 4)] = accJ[j];
        o[j * BLOCK + 2 * (SEQ_L / 4)] = accM[j];
        o[j * BLOCK + 3 * (SEQ_L / 4)] = accK[j];
    }
}

// ---------------- fallback: full complex output (if harness ever wants it) ---
__global__ __launch_bounds__(BLOCK) void s4_cauchy_complex_kernel(
    const float* __restrict__ log_dt, const float* __restrict__ A_real,
    const float* __restrict__ A_imag, const float* __restrict__ C,
    float* __restrict__ out)
{
    __shared__ float s_abr[D_STATE], s_abi[D_STATE], s_nr[D_STATE], s_ni[D_STATE];
    const int d    = blockIdx.x / (SEQ_L / BLOCK);
    const int lblk = blockIdx.x % (SEQ_L / BLOCK);
    const int tid  = threadIdx.x;
    if (tid < D_STATE) {
        const int n = tid;
        const float dt = __expf(log_dt[d]);
        const float ar = A_real[d * D_STATE + n], ai = A_imag[d * D_STATE + n];
        const float xr = 0.5f * dt * ar, xi = 0.5f * dt * ai;
        const float dr = 1.0f - xr, di = -xi;
        const float inv = 1.0f / (dr * dr + di * di);
        const float pr = 1.0f + xr, pi = xi;
        s_abr[n] = (pr * dr + pi * di) * inv;
        s_abi[n] = (pi * dr - pr * di) * inv;
        const float bbr = dt * dr * inv, bbi = -dt * di * inv;
        const float cr = C[(d * D_STATE + n) * 2 + 0], ci = C[(d * D_STATE + n) * 2 + 1];
        s_nr[n] = cr * bbr - ci * bbi;
        s_ni[n] = cr * bbi + ci * bbr;
    }
    __syncthreads();
    const int l = lblk * BLOCK + tid;
    const float theta = (2.0f * 3.14159265358979323846f * (float)l) / (float)SEQ_L;
    float s, c; __sincosf(theta, &s, &c);
    const float zr = c, zi = -s;
    float accr = 0.f, acci = 0.f;
#pragma unroll
    for (int n = 0; n < D_STATE; ++n) {
        const float abr = s_abr[n], abi = s_abi[n], nr = s_nr[n], ni = s_ni[n];
        const float dr = 1.0f - (abr * zr - abi * zi);
        const float di = -(abr * zi + abi * zr);
        const float inv = __builtin_amdgcn_rcpf(dr * dr + di * di);
        accr += (nr * dr + ni * di) * inv;
        acci += (ni * dr - nr * di) * inv;
    }
    float2* o = reinterpret_cast<float2*>(out);
    o[d * SEQ_L + l] = make_float2(accr, acci);
}

extern "C" void kernel_launch(void* const* d_in, const int* in_sizes, int n_in,
                              void* d_out, int out_size, void* d_ws, size_t ws_size,
                              hipStream_t stream) {
    const float* log_dt = (const float*)d_in[0];
    const float* A_real = (const float*)d_in[1];
    const float* A_imag = (const float*)d_in[2];
    const float* C      = (const float*)d_in[3];
    float* out = (float*)d_out;

    if (out_size >= 2 * D_MODEL * SEQ_L) {
        dim3 grid(D_MODEL * (SEQ_L / BLOCK));
        s4_cauchy_complex_kernel<<<grid, dim3(BLOCK), 0, stream>>>(log_dt, A_real, A_imag, C, out);
    } else {
        dim3 grid(D_MODEL);   // one block per d; each thread does 8 l's
        s4_cauchy_real_kernel<<<grid, dim3(BLOCK), 0, stream>>>(log_dt, A_real, A_imag, C, out);
    }
}